// Round 4
// baseline (13.448 us; speedup 1.0000x reference)
//
#include <hip/hip_runtime.h>

namespace {
constexpr int IC = 32;
constexpr int OC = 32;
constexpr int HW = 1024;            // 32*32 spatial
constexpr int H2 = 16, W2 = 16;     // pooled dims

typedef _Float16 half2v __attribute__((ext_vector_type(2)));

#if defined(__has_builtin)
#if __has_builtin(__builtin_amdgcn_fdot2)
#define HAVE_FDOT2 1
#endif
#endif

__device__ __forceinline__ float dot2acc(half2v a, half2v b, float c) {
#ifdef HAVE_FDOT2
    return __builtin_amdgcn_fdot2(a, b, c, false);   // v_dot2_f32_f16
#else
    return fmaf((float)a.x, (float)b.x, fmaf((float)a.y, (float)b.y, c));
#endif
}

__device__ __forceinline__ half2v u2h(unsigned int u) {
    union { unsigned int u; half2v h; } x; x.u = u; return x.h;
}

__device__ __forceinline__ half2v pk2(float a, float b) {
    union { decltype(__builtin_amdgcn_cvt_pkrtz(0.f, 0.f)) p; half2v h; } x;
    x.p = __builtin_amdgcn_cvt_pkrtz(a, b);   // v_cvt_pkrtz_f16_f32
    return x.h;
}
}

// Block = 512 threads (8 waves), tile 8n x 8o x one strip (2 h-rows x 32 w = 64 pos).
// Grid 512 = 32 tiles x 16 strips; bid = tt*16 + s -> XCD(bid%8)=s%8 keeps a strip's
// x/logits re-reads on one XCD's L2.
// SINGLE-BARRIER pipeline: P0 stages exp(x) full + exp(logits) full (16 float4
// loads/thread), one __syncthreads, P1 does all compute + epilogue. The 2 resident
// blocks/CU run complementary phases (P0 = VMEM/trans/LDS-write, P1 = LDS-read/VALU)
// -> scheduler-level software pipeline with no mid-kernel rendezvous.
// Denominators are per-thread (no wsl round-trip -> no second barrier needed).
// Epilogue pools PRODUCTS before the log: 4x fewer v_log_f32.
// LDS layout (per array, 32 KB): h2-index (row*64+p)*16 + ((ip>>2)^sw(p))*4 + (ip&3),
// sw(p)=((p>>1)^(p>>3))&3 -> all compute reads are conflict-free ds_read_b128
// (verified per 8-lane phase group); staging writes <=2-way (free).
__global__ __launch_bounds__(512, 4) void sumprod_fused(
    const float* __restrict__ x, const float* __restrict__ logits,
    float* __restrict__ out)
{
    __shared__ half2v exl[8 * 64 * 16];   // exp(x)   [n8][p64][16 ip slots] 32 KB
    __shared__ half2v ewl[8 * 64 * 16];   // exp(lgt) [o8][p64][16 ip slots] 32 KB

    const int tid  = threadIdx.x;
    const int lane = tid & 63;
    const int w    = tid >> 6;          // wave id = staging row (n and o)
    const int bid  = blockIdx.x;
    const int s    = bid & 15;          // strip (== h2)
    const int tt   = bid >> 4;          // 0..31
    const int n0   = (tt & 7) * 8;
    const int o0   = (tt >> 3) * 8;

    const int kk    = (tid >> 4) & 3;   // element slot within b128 group
    const int p4    = tid & 15;         // float4 slot in strip
    const int spoff = (2 * s + (p4 >> 3)) * 32 + (p4 & 7) * 4;

    const float* gx = x      + (size_t)(n0 + w) * IC * HW + spoff;
    const float* gw = logits + (size_t)(o0 + w) * IC * HW + spoff;

    // exp + pack f16 pair + swizzled LDS write of one float4-pair task
    auto stage = [&](half2v* buf, const float4& va, const float4& vb, int ip) {
        const float* pa = reinterpret_cast<const float*>(&va);
        const float* pb = reinterpret_cast<const float*>(&vb);
        #pragma unroll
        for (int j = 0; j < 4; ++j) {
            const int p    = (p4 >> 3) * 32 + (p4 & 7) * 4 + j;
            const int slot = (ip >> 2) ^ (((p >> 1) ^ (p >> 3)) & 3);
            buf[(w * 64 + p) * 16 + slot * 4 + (ip & 3)] =
                pk2(__expf(pa[j]), __expf(pb[j]));
        }
    };

    // ---- P0: stage exp(logits) full (ip 0..15) + exp(x) full (ip 0..15)
    #pragma unroll
    for (int g = 0; g < 4; ++g) {
        const int ip = g * 4 + kk;
        const float4 va = *reinterpret_cast<const float4*>(&gw[(2 * ip) * HW]);
        const float4 vb = *reinterpret_cast<const float4*>(&gw[(2 * ip + 1) * HW]);
        stage(ewl, va, vb, ip);
    }
    #pragma unroll
    for (int g = 0; g < 4; ++g) {
        const int ip = g * 4 + kk;
        const float4 va = *reinterpret_cast<const float4*>(&gx[(2 * ip) * HW]);
        const float4 vb = *reinterpret_cast<const float4*>(&gx[(2 * ip + 1) * HW]);
        stage(exl, va, vb, ip);
    }
    __syncthreads();   // the only barrier

    const int swl = ((lane >> 1) ^ (lane >> 3)) & 3;
    const int nw = (w & 1) * 4;
    const int ow = (w >> 1) * 2;

    // ---- P1a: per-thread softmax denominators for rows ow, ow+1 at this lane
    const half2v one2 = {(_Float16)1.f, (_Float16)1.f};
    float den[2];
    #pragma unroll
    for (int j = 0; j < 2; ++j) {
        float ds = 0.f;
        const half2v* rb = &ewl[((ow + j) * 64 + lane) * 16];
        #pragma unroll
        for (int gg = 0; gg < 4; ++gg) {
            const uint4 B = *reinterpret_cast<const uint4*>(rb + ((gg ^ swl) * 4));
            ds = dot2acc(u2h(B.x), one2, ds);
            ds = dot2acc(u2h(B.y), one2, ds);
            ds = dot2acc(u2h(B.z), one2, ds);
            ds = dot2acc(u2h(B.w), one2, ds);
        }
        den[j] = ds;
    }

    // ---- P1b: compute, wave tile 4n x 2o, lane = position
    float acc[4][2] = {};

#define D2(AA, BB, K, J) acc[K][J] = dot2acc(u2h(AA), u2h(BB), acc[K][J])
#define QUAD(A_, K_)                                                          \
    D2(A_.x, B0.x, K_, 0); D2(A_.y, B0.y, K_, 0);                             \
    D2(A_.z, B0.z, K_, 0); D2(A_.w, B0.w, K_, 0);                             \
    D2(A_.x, B1.x, K_, 1); D2(A_.y, B1.y, K_, 1);                             \
    D2(A_.z, B1.z, K_, 1); D2(A_.w, B1.w, K_, 1)
#define COMPUTE_GG(GG) {                                                      \
    const int off = ((GG) ^ swl) * 4;                                         \
    const uint4 A0 = *reinterpret_cast<const uint4*>(&exl[((nw + 0) * 64 + lane) * 16 + off]); \
    const uint4 A1 = *reinterpret_cast<const uint4*>(&exl[((nw + 1) * 64 + lane) * 16 + off]); \
    const uint4 A2 = *reinterpret_cast<const uint4*>(&exl[((nw + 2) * 64 + lane) * 16 + off]); \
    const uint4 A3 = *reinterpret_cast<const uint4*>(&exl[((nw + 3) * 64 + lane) * 16 + off]); \
    const uint4 B0 = *reinterpret_cast<const uint4*>(&ewl[((ow + 0) * 64 + lane) * 16 + off]); \
    const uint4 B1 = *reinterpret_cast<const uint4*>(&ewl[((ow + 1) * 64 + lane) * 16 + off]); \
    QUAD(A0, 0); QUAD(A1, 1); QUAD(A2, 2); QUAD(A3, 3); }

    COMPUTE_GG(0);
    COMPUTE_GG(1);
    COMPUTE_GG(2);
    COMPUTE_GG(3);

#undef COMPUTE_GG
#undef QUAD
#undef D2

    // ---- epilogue: pool PRODUCTS over the 2x2 window, then a single log.
    //  sum_{4 pos} (log acc_p - log den_p) = log(prod acc_p) - log(prod den_p)
    float dp0 = den[0];
    dp0 *= __shfl_xor(dp0, 1);  dp0 *= __shfl_xor(dp0, 32);
    float dp1 = den[1];
    dp1 *= __shfl_xor(dp1, 1);  dp1 *= __shfl_xor(dp1, 32);

    #pragma unroll
    for (int k = 0; k < 4; ++k) {
        #pragma unroll
        for (int j = 0; j < 2; ++j) {
            float v = acc[k][j];
            v *= __shfl_xor(v, 1);    // pool over w-pair
            v *= __shfl_xor(v, 32);   // pool over h-pair
            if ((lane & 33) == 0) {   // even lane, h_lo == 0
                const int w2 = (lane >> 1) & 15;
                out[((n0 + nw + k) * OC + (o0 + ow + j)) * (H2 * W2) + s * W2 + w2] =
                    __logf(v) - __logf(j ? dp1 : dp0);
            }
        }
    }
}

extern "C" void kernel_launch(void* const* d_in, const int* in_sizes, int n_in,
                              void* d_out, int out_size, void* d_ws, size_t ws_size,
                              hipStream_t stream) {
    const float* x      = (const float*)d_in[0];
    const float* logits = (const float*)d_in[1];
    float* out = (float*)d_out;
    hipLaunchKernelGGL(sumprod_fused, dim3(512), dim3(512), 0, stream,
                       x, logits, out);
}